// Round 19
// baseline (345.162 us; speedup 1.0000x reference)
//
#include <hip/hip_runtime.h>

// TMMixer: B=64, T=64, S=256, DIM=768, H=12, HD=64, RANK=64
//  1. transpose weights -> bf16; wtkv stacked; wtoU[768][832] = wo|lora_up; dT padded to 128 rows
//  2. LN1 -> bf16
//  3. gemm_proj: q + kv projections (pure, 2-way)
//  4. attn_mfma dispatch = lora-z-down (64 blocks, fills attn's ramp) + attention (1536)
//  5. gemm_post: (wo|up) K=832 GEMM + resid -> zbuf  AND  fusion_prep2 in ONE dispatch
//  6. fusion_ln2_mlp v6: 512 threads / 8 waves / 2 rows per wave, launch_bounds(512,8)
//     forces VGPR<=64 -> 4 blocks x 8 waves = 32 waves/CU (TLP, was 24)

typedef __bf16 bf8_t __attribute__((ext_vector_type(8)));
typedef float f4_t __attribute__((ext_vector_type(4)));
typedef unsigned short u16;
typedef unsigned int u32;
typedef unsigned long long u64;
typedef unsigned short us4_t __attribute__((ext_vector_type(4)));
typedef unsigned short us8_t __attribute__((ext_vector_type(8)));

__device__ __forceinline__ float bf2f(u16 h) {
    return __uint_as_float(((unsigned int)h) << 16);
}
__device__ __forceinline__ u16 f2bf(float f) {
    unsigned int u = __float_as_uint(f);
    u += 0x7fffu + ((u >> 16) & 1u);
    return (u16)(u >> 16);
}
__device__ __forceinline__ float gelu_tanh(float x) {
    float t = tanhf(0.7978845608028654f * (x + 0.044715f * x * x * x));
    return 0.5f * x * (1.0f + t);
}
__device__ __forceinline__ void load_lds16(const void* g, void* l) {
    __builtin_amdgcn_global_load_lds(
        (const __attribute__((address_space(1))) unsigned int*)g,
        (__attribute__((address_space(3))) unsigned int*)l, 16, 0, 0);
}

// ---------------- weight prep ----------------
struct TPack {
    const float* s0; const float* s1; const float* s2; const float* s3;
    u16* d0; u16* d1; u16* d2; u16* d3;
};
__global__ __launch_bounds__(256) void transpose_big(TPack p) {
    int which = blockIdx.y;
    const float* src = which == 0 ? p.s0 : which == 1 ? p.s1 : which == 2 ? p.s2 : p.s3;
    u16* dst = which == 0 ? p.d0 : which == 1 ? p.d1 : which == 2 ? p.d2 : p.d3;
    int idx = blockIdx.x * 256 + threadIdx.x;  // 768*768
    int c = idx / 768, r = idx - c * 768;
    u16 v = f2bf(src[(size_t)r * 768 + c]);
    if (which == 3) dst[(size_t)c * 832 + r] = v;   // wtoU k-cols 0..767
    else dst[idx] = v;
}
__global__ __launch_bounds__(256) void transpose_small(TPack p) {
    int which = blockIdx.y;
    const float* src = which == 0 ? p.s0 : which == 1 ? p.s1 : which == 2 ? p.s2 : p.s3;
    u16* dst = which == 0 ? p.d0 : which == 1 ? p.d1 : which == 2 ? p.d2 : p.d3;
    int R = (which & 1) ? 64 : 768;
    int C = (which & 1) ? 768 : 64;
    int idx = blockIdx.x * 256 + threadIdx.x;  // 49152
    int c = idx / R, r = idx - c * R;
    u16 v = f2bf(src[(size_t)r * C + c]);
    if (which == 1) dst[(size_t)c * 832 + r] = v;   // wtoU+768: k-cols 768..831
    else dst[idx] = v;
}

// ---------------- LN1: wave-per-row, f4 loads ----------
__global__ __launch_bounds__(256) void ln1_kernel(
    const float* __restrict__ x0, const float* __restrict__ x1,
    const float* __restrict__ w, const float* __restrict__ b,
    u16* __restrict__ lnZ, u16* __restrict__ lnX) {
    int rid = blockIdx.x * 4 + (threadIdx.x >> 6);
    int lane = threadIdx.x & 63;
    int s = rid / 20480;
    int r2 = rid - s * 20480;
    const float* srcBase = (s == 0) ? x0 : x1;
    const float* src; u16* dst;
    if (r2 < 4096) {
        int bb = r2 >> 6, t = r2 & 63;
        src = srcBase + ((size_t)(bb * 320 + t)) * 768;
        dst = lnZ + ((size_t)(s * 4096 + r2)) * 768;
    } else {
        int rx = r2 - 4096;
        int bb = rx >> 8, sx = rx & 255;
        src = srcBase + ((size_t)(bb * 320 + 64 + sx)) * 768;
        dst = lnX + ((size_t)(s * 16384 + rx)) * 768;
    }
    f4_t v[3];
    float s1 = 0.f, s2 = 0.f;
    #pragma unroll
    for (int jj = 0; jj < 3; jj++) {
        v[jj] = *reinterpret_cast<const f4_t*>(src + (lane + 64 * jj) * 4);
        #pragma unroll
        for (int e = 0; e < 4; e++) { s1 += v[jj][e]; s2 += v[jj][e] * v[jj][e]; }
    }
    #pragma unroll
    for (int o = 1; o < 64; o <<= 1) { s1 += __shfl_xor(s1, o); s2 += __shfl_xor(s2, o); }
    float mean = s1 * (1.0f / 768.0f);
    float var = s2 * (1.0f / 768.0f) - mean * mean;
    float rstd = rsqrtf(var + 1e-5f);
    #pragma unroll
    for (int jj = 0; jj < 3; jj++) {
        int c0 = (lane + 64 * jj) * 4;
        f4_t wv = *reinterpret_cast<const f4_t*>(w + c0);
        f4_t bv = *reinterpret_cast<const f4_t*>(b + c0);
        us4_t o4;
        #pragma unroll
        for (int e = 0; e < 4; e++)
            o4[e] = f2bf((v[jj][e] - mean) * rstd * wv[e] + bv[e]);
        *reinterpret_cast<us4_t*>(dst + c0) = o4;
    }
}

// ---------------- shared MFMA GEMM core: C = A(MxKT) * Bt(NxKT)^T ---------
enum { EPI_BF16 = 0, EPI_RESID_Z = 1, EPI_GELU64 = 2 };

template <int BM, int BN, int WR, int WC, int EPI, int KT>
__device__ __forceinline__ void gemm_core(
    u16* shA, u16* shB,
    const u16* __restrict__ A, const u16* __restrict__ Bt,
    int M, int N, int ldc, int xb, int bid,
    float* __restrict__ Cf, u16* __restrict__ Cbf,
    const float* __restrict__ resid0, const float* __restrict__ resid1) {
    constexpr int THREADS = WR * WC * 64;
    constexpr int NW = THREADS / 64;
    constexpr int BK = 64;

    const int tid = threadIdx.x;
    const int lane = tid & 63;
    const int w = tid >> 6;
    const int wr = w / WC, wc = w % WC;
    const int r = lane & 15, g = lane >> 4;
    const int gx = N / BN;
    const int panels = (M / BM) >> 3;   // requires (M/BM)%8==0
    int xcd = bid & 7, local = bid >> 3;
    const int bcol = (local % gx) * BN;
    const int brow = (xcd * panels + local / gx) * BM;

    const int srow = lane >> 3;            // row within 8-row chunk
    const int scol = (lane & 7) ^ srow;    // pre-swizzled 16B-chunk index
    const int rsw = r & 7;                 // read-side swizzle key
    const int csw0 = (g ^ rsw) * 8;
    const int csw1 = ((g + 4) ^ rsw) * 8;
    int aoff[4], boff[4];
    #pragma unroll
    for (int m = 0; m < 4; m++) aoff[m] = (wr * 64 + m * 16 + r) * 64;
    #pragma unroll
    for (int n = 0; n < 4; n++) boff[n] = (wc * 64 + n * 16 + r) * 64;

    f4_t acc[4][4];
    f4_t zero = {0.f, 0.f, 0.f, 0.f};
    #pragma unroll
    for (int m = 0; m < 4; m++)
        #pragma unroll
        for (int n = 0; n < 4; n++) acc[m][n] = zero;

    for (int k0 = 0; k0 < KT; k0 += BK) {
        #pragma unroll
        for (int c = 0; c < BM / 8 / NW; c++) {
            int chunk = w + c * NW;
            int row = chunk * 8 + srow;
            load_lds16(A + (size_t)(brow + row) * KT + k0 + scol * 8, shA + chunk * 512);
        }
        #pragma unroll
        for (int c = 0; c < BN / 8 / NW; c++) {
            int chunk = w + c * NW;
            int row = chunk * 8 + srow;
            load_lds16(Bt + (size_t)(bcol + row) * KT + k0 + scol * 8, shB + chunk * 512);
        }
        __syncthreads();
        {
            bf8_t af[4], bfr[4];
            #pragma unroll
            for (int m = 0; m < 4; m++)
                af[m] = *reinterpret_cast<const bf8_t*>(&shA[aoff[m] + csw0]);
            #pragma unroll
            for (int n = 0; n < 4; n++)
                bfr[n] = *reinterpret_cast<const bf8_t*>(&shB[boff[n] + csw0]);
            #pragma unroll
            for (int m = 0; m < 4; m++)
                #pragma unroll
                for (int n = 0; n < 4; n++)
                    acc[m][n] = __builtin_amdgcn_mfma_f32_16x16x32_bf16(af[m], bfr[n], acc[m][n], 0, 0, 0);
            #pragma unroll
            for (int m = 0; m < 4; m++)
                af[m] = *reinterpret_cast<const bf8_t*>(&shA[aoff[m] + csw1]);
            #pragma unroll
            for (int n = 0; n < 4; n++)
                bfr[n] = *reinterpret_cast<const bf8_t*>(&shB[boff[n] + csw1]);
            #pragma unroll
            for (int m = 0; m < 4; m++)
                #pragma unroll
                for (int n = 0; n < 4; n++)
                    acc[m][n] = __builtin_amdgcn_mfma_f32_16x16x32_bf16(af[m], bfr[n], acc[m][n], 0, 0, 0);
        }
        __syncthreads();
    }

    #pragma unroll
    for (int m = 0; m < 4; m++) {
        #pragma unroll
        for (int n = 0; n < 4; n++) {
            int col = bcol + wc * 64 + n * 16 + r;
            #pragma unroll
            for (int i = 0; i < 4; i++) {
                int row = brow + wr * 64 + m * 16 + g * 4 + i;
                int orow = row ^ xb;
                float val = acc[m][n][i];
                if constexpr (EPI == EPI_BF16) {
                    Cbf[(size_t)orow * ldc + col] = f2bf(val);
                } else if constexpr (EPI == EPI_RESID_Z) {
                    int s = orow >> 12, bb = (orow >> 6) & 63, t = orow & 63;
                    const float* rp = (s != 0) ? resid1 : resid0;
                    float rs = rp[((size_t)bb * 320 + t) * 768 + col];
                    Cf[(size_t)orow * 768 + col] = val + rs;   // compact zbuf
                } else if constexpr (EPI == EPI_GELU64) {
                    if (col < 64)   // N padded to 128; cols 64..127 are junk
                        Cbf[(size_t)orow * ldc + col] = f2bf(gelu_tanh(val));
                }
            }
        }
    }
}

// ---------------- gemm_proj: q (384) | kv (3072) -- pure 2-way ------------
struct ProjArgs {
    const u16* lnZ; const u16* lnX; const u16* wtq; const u16* wtkv;
    u16* qb; u16* kvb;
};
__global__ __launch_bounds__(256, 1) void gemm_proj(ProjArgs a) {
    __shared__ alignas(16) u16 SH[16384];   // 32 KB
    int bid = blockIdx.x;
    if (bid < 384) {
        gemm_core<128, 128, 2, 2, EPI_BF16, 768>(
            SH, SH + 8192, a.lnZ, a.wtq, 8192, 768, 768, 0, bid,
            nullptr, a.qb, nullptr, nullptr);
    } else {
        gemm_core<128, 128, 2, 2, EPI_BF16, 768>(
            SH, SH + 8192, a.lnX, a.wtkv, 32768, 1536, 1536, 16384, bid - 384,
            nullptr, a.kvb, nullptr, nullptr);
    }
}

// ---------------- attn dispatch: lora-down (64) + attention (1536) --------
struct AttnArgs {
    const u16* q; const u16* kv; u16* aoh; u16* paff;
    const u16* lnZ; const u16* dT; u16* aohL;   // aohL = aoh + 768
};
__global__ __launch_bounds__(256, 2) void attn_mfma(AttnArgs a) {
    __shared__ alignas(16) u16 Ks[256][72];   // 36,864 B (P tiles alias after sync)
    __shared__ alignas(16) u16 Vt[64][264];   // 33,792 B
    int bid0 = blockIdx.x;
    if (bid0 < 64) {
        // lora-z down: gelu(lnZ @ dT^T), row^4096; dT padded to N=128
        u16* SH = &Ks[0][0];   // 32 KB carve of attn's 70.7 KB LDS
        gemm_core<128, 128, 2, 2, EPI_GELU64, 768>(
            SH, SH + 8192, a.lnZ, a.dT, 8192, 128, 832, 4096, bid0,
            nullptr, a.aohL, nullptr, nullptr);
        return;
    }
    int bid = bid0 - 64;
    const u16* q = a.q;
    const u16* kv = a.kv;
    u16* aoh = a.aoh;
    u16* paff = a.paff;
    int s = bid / 768;
    int rem = bid - s * 768;
    int b = rem / 12, h = rem - (rem / 12) * 12;
    int tid = threadIdx.x, lane = tid & 63, w = tid >> 6;
    int r = lane & 15, g = lane >> 4;

    size_t kvbase = ((size_t)(s * 16384 + b * 256)) * 1536 + h * 64;

    const u16* qrow = q + ((size_t)(s * 4096 + b * 64 + w * 16 + r)) * 768 + h * 64 + g * 8;
    bf8_t qf0 = *reinterpret_cast<const bf8_t*>(qrow);
    bf8_t qf1 = *reinterpret_cast<const bf8_t*>(qrow + 32);

    #pragma unroll
    for (int i = 0; i < 8; i++) {
        int c = tid + 256 * i;
        int row = c >> 3, kc = (c & 7) * 8;
        *reinterpret_cast<bf8_t*>(&Ks[row][kc]) =
            *reinterpret_cast<const bf8_t*>(kv + kvbase + (size_t)row * 1536 + kc);
    }
    u32* vt32 = reinterpret_cast<u32*>(&Vt[0][0]);  // row stride 132 u32
    #pragma unroll
    for (int i = 0; i < 4; i++) {
        int c = tid + 256 * i;
        int kp = c >> 3, d0 = (c & 7) * 8;
        const u16* vr = kv + kvbase + 768 + (size_t)(2 * kp) * 1536 + d0;
        us8_t va = *reinterpret_cast<const us8_t*>(vr);
        us8_t vb = *reinterpret_cast<const us8_t*>(vr + 1536);
        #pragma unroll
        for (int j = 0; j < 8; j++)
            vt32[(d0 + j) * 132 + kp] = (u32)va[j] | ((u32)vb[j] << 16);
    }
    __syncthreads();

    f4_t acc[16];
    f4_t zero = {0.f, 0.f, 0.f, 0.f};
    #pragma unroll
    for (int n = 0; n < 16; n++) acc[n] = zero;
    #pragma unroll
    for (int n = 0; n < 16; n++) {
        bf8_t b0 = *reinterpret_cast<const bf8_t*>(&Ks[n * 16 + r][g * 8]);
        acc[n] = __builtin_amdgcn_mfma_f32_16x16x32_bf16(qf0, b0, acc[n], 0, 0, 0);
        bf8_t b1 = *reinterpret_cast<const bf8_t*>(&Ks[n * 16 + r][32 + g * 8]);
        acc[n] = __builtin_amdgcn_mfma_f32_16x16x32_bf16(qf1, b1, acc[n], 0, 0, 0);
    }

    float mx[4] = {-1e30f, -1e30f, -1e30f, -1e30f};
    #pragma unroll
    for (int n = 0; n < 16; n++)
        #pragma unroll
        for (int i = 0; i < 4; i++) {
            acc[n][i] *= 0.125f;
            mx[i] = fmaxf(mx[i], acc[n][i]);
        }
    #pragma unroll
    for (int i = 0; i < 4; i++) {
        mx[i] = fmaxf(mx[i], __shfl_xor(mx[i], 1));
        mx[i] = fmaxf(mx[i], __shfl_xor(mx[i], 2));
        mx[i] = fmaxf(mx[i], __shfl_xor(mx[i], 4));
        mx[i] = fmaxf(mx[i], __shfl_xor(mx[i], 8));
    }
    float sm[4] = {0.f, 0.f, 0.f, 0.f};
    #pragma unroll
    for (int n = 0; n < 16; n++)
        #pragma unroll
        for (int i = 0; i < 4; i++) {
            float e = __expf(acc[n][i] - mx[i]);
            acc[n][i] = e;
            sm[i] += e;
        }
    #pragma unroll
    for (int i = 0; i < 4; i++) {
        sm[i] += __shfl_xor(sm[i], 1);
        sm[i] += __shfl_xor(sm[i], 2);
        sm[i] += __shfl_xor(sm[i], 4);
        sm[i] += __shfl_xor(sm[i], 8);
    }
    float inv[4];
    #pragma unroll
    for (int i = 0; i < 4; i++) inv[i] = 1.0f / sm[i];

    __syncthreads();  // all waves done reading Ks; safe to overwrite with P

    u16* Pw = &Ks[w * 64][0];
    u16* pout = paff + ((size_t)bid * 64 + w * 16) * 256;
    #pragma unroll
    for (int n = 0; n < 16; n++) {
        int kcol = n * 16 + r;
        #pragma unroll
        for (int i = 0; i < 4; i++) {
            u16 pb = f2bf(acc[n][i] * inv[i]);
            Pw[(g * 4 + i) * 264 + kcol] = pb;
            pout[(g * 4 + i) * 256 + kcol] = pb;
        }
    }

    f4_t acc2[4];
    #pragma unroll
    for (int n = 0; n < 4; n++) acc2[n] = zero;
    #pragma unroll
    for (int k2 = 0; k2 < 8; k2++) {
        bf8_t pa = *reinterpret_cast<const bf8_t*>(&Pw[r * 264 + k2 * 32 + g * 8]);
        #pragma unroll
        for (int n2 = 0; n2 < 4; n2++) {
            bf8_t vbf = *reinterpret_cast<const bf8_t*>(&Vt[n2 * 16 + r][k2 * 32 + g * 8]);
            acc2[n2] = __builtin_amdgcn_mfma_f32_16x16x32_bf16(pa, vbf, acc2[n2], 0, 0, 0);
        }
    }
    u16* op = aoh + ((size_t)(s * 4096 + b * 64 + w * 16 + g * 4)) * 832 + h * 64;
    #pragma unroll
    for (int n2 = 0; n2 < 4; n2++)
        #pragma unroll
        for (int i = 0; i < 4; i++)
            op[(size_t)i * 832 + n2 * 16 + r] = f2bf(acc2[n2][i]);
}

// ---------------- prep2 body (device): h-sum -> colmax -> nu/den/winners --
__device__ __forceinline__ void prep2_body(
    int idx, const u16* __restrict__ paff, float* __restrict__ aff,
    float* __restrict__ den, u64* __restrict__ winners, float* red) {
    int sb = idx & 127, qc = idx >> 7;
    int t = threadIdx.x, lane = t & 63, w = t >> 6;
    int q0 = qc * 16;
    float a[16];
    #pragma unroll
    for (int j = 0; j < 16; j++) a[j] = 0.f;
    size_t base = ((size_t)sb * 12 * 64 + q0) * 256 + t;
    for (int h = 0; h < 12; h++) {
        size_t hb = base + (size_t)h * 64 * 256;
        #pragma unroll
        for (int j = 0; j < 16; j++) a[j] += bf2f(paff[hb + j * 256]);
    }
    float m[16];
    #pragma unroll
    for (int j = 0; j < 16; j++) {
        float v = a[j];
        #pragma unroll
        for (int o = 1; o < 64; o <<= 1) v = fmaxf(v, __shfl_xor(v, o));
        m[j] = v;
    }
    if (lane == 0) {
        #pragma unroll
        for (int j = 0; j < 16; j++) red[j * 4 + w] = m[j];
    }
    __syncthreads();
    float dsum = 0.f;
    u64 wmask = 0;
    float nu[16];
    #pragma unroll
    for (int j = 0; j < 16; j++) {
        float cm = fmaxf(fmaxf(red[j * 4 + 0], red[j * 4 + 1]),
                         fmaxf(red[j * 4 + 2], red[j * 4 + 3]));
        nu[j] = (a[j] == cm) ? __expf(a[j] - 12.0f) : 0.f;
        if (nu[j] != 0.f) wmask |= (u64)1 << (q0 + j);
        dsum += nu[j];
    }
    if (dsum != 0.f) atomicAdd(&den[sb * 256 + t], dsum);
    if (wmask) atomicOr(&winners[(size_t)sb * 256 + t], wmask);
    float* ap = aff + ((size_t)sb * 256 + t) * 64 + q0;
    #pragma unroll
    for (int j = 0; j < 16; j++) ap[j] = nu[j];
}

// ---------------- gemm_post: wo|up GEMM (384) | fusion_prep2 (512) --------
struct PostArgs {
    const u16* aoh; const u16* wtoU; float* zbuf;
    const float* x0; const float* x1;
    const u16* paff; float* aff; float* den; u64* winners;
};
__global__ __launch_bounds__(256, 1) void gemm_post(PostArgs a) {
    __shared__ alignas(16) u16 SH[16384];   // 32 KB
    int bid = blockIdx.x;
    if (bid < 384) {
        gemm_core<128, 128, 2, 2, EPI_RESID_Z, 832>(
            SH, SH + 8192, a.aoh, a.wtoU, 8192, 768, 768, 0, bid,
            a.zbuf, nullptr, a.x0, a.x1);
    } else {
        prep2_body(bid - 384, a.paff, a.aff, a.den, a.winners, (float*)SH);
    }
}

// ---------------- fusion_ln2_mlp v6: 512 threads, 2 rows/wave, VGPR<=64 ---
// 16 rows/block, 8 waves. Phase 1 on waves 0-3 only; phase 2 split 8 ways.
__global__ __launch_bounds__(512, 8) void fusion_ln2_mlp(
    const float* __restrict__ x0, const float* __restrict__ x1,
    const float* __restrict__ zbuf, const float* __restrict__ aff,
    const float* __restrict__ den, const u64* __restrict__ winners,
    float* __restrict__ out, const float* __restrict__ w2,
    const float* __restrict__ b2, const u16* __restrict__ mdT,
    const u16* __restrict__ muT) {
    __shared__ alignas(16) u16 A[16][776];   // 24,832 B; reused for up-contribution
    __shared__ alignas(16) u16 Hs[16][72];   //  2,304 B
    int tid = threadIdx.x, lane = tid & 63, w = tid >> 6;   // w in 0..7
    int r = lane & 15, g = lane >> 4;
    int rbase = blockIdx.x * 16;

    // phase 0: per-wave 2 rows; metadata -> base loads -> gathers -> LN -> A
    f4_t p[2][3];
    #pragma unroll
    for (int rr = 0; rr < 2; rr++) {
        int row = w * 2 + rr;
        int rid = rbase + row;
        int s = rid / 20480;
        int r2 = rid - s * 20480;
        int b = r2 / 320, n = r2 - (r2 / 320) * 320;
        const float* srcp;
        float scale;
        u64 mask;
        const float* zrbase = zbuf + ((size_t)(s * 4096 + b * 64)) * 768;
        const float* affbase = nullptr;
        if (n < 64) {
            srcp = zrbase + (size_t)n * 768;
            scale = 1.0f;
            mask = 0;
        } else {
            int sx = n - 64;
            int sb = s * 64 + b;
            srcp = ((s == 0) ? x0 : x1) + ((size_t)(b * 320 + n)) * 768;
            scale = 1.0f / (1.0f + den[sb * 256 + sx]);
            mask = winners[(size_t)sb * 256 + sx];
            affbase = aff + ((size_t)sb * 256 + sx) * 64;
        }
        #pragma unroll
        for (int cc = 0; cc < 3; cc++)
            p[rr][cc] = *reinterpret_cast<const f4_t*>(srcp + cc * 256 + lane * 4) * scale;
        while (mask) {
            int t = (int)__builtin_ctzll(mask);
            mask &= mask - 1;
            float wgt = affbase[t] * scale;
            const float* zr = zrbase + (size_t)t * 768;
            #pragma unroll
            for (int cc = 0; cc < 3; cc++)
                p[rr][cc] += *reinterpret_cast<const f4_t*>(zr + cc * 256 + lane * 4) * wgt;
        }
        float a1 = 0.f, a2 = 0.f;
        #pragma unroll
        for (int cc = 0; cc < 3; cc++)
            #pragma unroll
            for (int e = 0; e < 4; e++) { a1 += p[rr][cc][e]; a2 += p[rr][cc][e] * p[rr][cc][e]; }
        #pragma unroll
        for (int o = 1; o < 64; o <<= 1) { a1 += __shfl_xor(a1, o); a2 += __shfl_xor(a2, o); }
        float mean = a1 * (1.0f / 768.0f);
        float var = a2 * (1.0f / 768.0f) - mean * mean;
        float rstd = rsqrtf(var + 1e-5f);
        #pragma unroll
        for (int cc = 0; cc < 3; cc++) {
            int c0 = cc * 256 + lane * 4;
            f4_t wv = *reinterpret_cast<const f4_t*>(w2 + c0);
            f4_t bv = *reinterpret_cast<const f4_t*>(b2 + c0);
            us4_t o4;
            #pragma unroll
            for (int e = 0; e < 4; e++)
                o4[e] = f2bf((p[rr][cc][e] - mean) * rstd * wv[e] + bv[e]);
            *reinterpret_cast<us4_t*>(&A[row][c0]) = o4;
        }
    }
    __syncthreads();

    // phase 1: down GEMM (M=16, N=64, K=768); waves 0-3 own N-tile w
    f4_t zero = {0.f, 0.f, 0.f, 0.f};
    if (w < 4) {
        f4_t hacc = zero;
        const u16* mrow = mdT + (size_t)(w * 16 + r) * 768 + g * 8;
        #pragma unroll
        for (int k0 = 0; k0 < 768; k0 += 32) {
            bf8_t af = *reinterpret_cast<const bf8_t*>(&A[r][k0 + g * 8]);
            bf8_t bf = *reinterpret_cast<const bf8_t*>(mrow + k0);
            hacc = __builtin_amdgcn_mfma_f32_16x16x32_bf16(af, bf, hacc, 0, 0, 0);
        }
        #pragma unroll
        for (int i = 0; i < 4; i++)
            Hs[g * 4 + i][w * 16 + r] = f2bf(gelu_tanh(hacc[i]));
    }
    __syncthreads();   // Hs ready; all A reads done

    // phase 2: up GEMM (M=16, N=768, K=64); wave w owns cols w*96..w*96+95
    bf8_t a0 = *reinterpret_cast<const bf8_t*>(&Hs[r][g * 8]);
    bf8_t a1 = *reinterpret_cast<const bf8_t*>(&Hs[r][32 + g * 8]);
    #pragma unroll
    for (int nn = 0; nn < 6; nn++) {
        int col = w * 96 + nn * 16 + r;
        bf8_t b0 = *reinterpret_cast<const bf8_t*>(muT + (size_t)col * 64 + g * 8);
        bf8_t b1 = *reinterpret_cast<const bf8_t*>(muT + (size_t)col * 64 + 32 + g * 8);
        f4_t c = __builtin_amdgcn_mfma_f32_16x16x32_bf16(a1, b1, zero, 0, 0, 0);
        c = __builtin_amdgcn_mfma_f32_16x16x32_bf16(a0, b0, c, 0, 0, 0);
        #pragma unroll
        for (int i = 0; i < 4; i++)
            A[g * 4 + i][col] = f2bf(c[i]);
    }
    __syncthreads();

    // phase 3: coalesced add + single store of out (2 rows per wave)
    #pragma unroll
    for (int rr = 0; rr < 2; rr++) {
        int row = w * 2 + rr;
        size_t orow = (size_t)(rbase + row) * 768;
        #pragma unroll
        for (int cc = 0; cc < 3; cc++) {
            int c0 = cc * 256 + lane * 4;
            us4_t c4 = *reinterpret_cast<const us4_t*>(&A[row][c0]);
            f4_t o = p[rr][cc];
            #pragma unroll
            for (int e = 0; e < 4; e++) o[e] += bf2f(c4[e]);
            *reinterpret_cast<f4_t*>(out + orow + c0) = o;
        }
    }
}

extern "C" void kernel_launch(void* const* d_in, const int* in_sizes, int n_in,
                              void* d_out, int out_size, void* d_ws, size_t ws_size,
                              hipStream_t stream) {
    (void)in_sizes; (void)n_in; (void)out_size;
    const float* x0 = (const float*)d_in[0];
    const float* x1 = (const float*)d_in[1];
    const float* ln1w = (const float*)d_in[2];
    const float* ln1b = (const float*)d_in[3];
    const float* ln2w = (const float*)d_in[4];
    const float* ln2b = (const float*)d_in[5];
    const float* wq = (const float*)d_in[6];
    const float* wk = (const float*)d_in[7];
    const float* wv = (const float*)d_in[8];
    const float* wo = (const float*)d_in[9];
    const float* lora_down = (const float*)d_in[10];
    const float* lora_up = (const float*)d_in[11];
    const float* mlp_down = (const float*)d_in[12];
    const float* mlp_up = (const float*)d_in[13];
    float* out = (float*)d_out;

    char* ws = (char*)d_ws;
    size_t off = 0;
    auto alloc = [&](size_t bytes) -> char* {
        char* p = ws + off;
        off = (off + bytes + 255) & ~(size_t)255;
        return p;
    };
    u16* wtq  = (u16*)alloc(768 * 768 * 2);
    u16* wtkv = (u16*)alloc((size_t)1536 * 768 * 2);
    u16* wtoU = (u16*)alloc((size_t)768 * 832 * 2);
    u16* dT  = (u16*)alloc((size_t)128 * 768 * 2);   // padded to 128 rows
    u16* mdT = (u16*)alloc(768 * 64 * 2);
    u16* muT = (u16*)alloc(768 * 64 * 2);
    u16* lnZ = (u16*)alloc((size_t)2 * 4096 * 768 * 2);
    u16* lnX = (u16*)alloc((size_t)2 * 16384 * 768 * 2);
    u16* qb  = (u16*)alloc((size_t)2 * 4096 * 768 * 2);
    u16* kvb = (u16*)alloc((size_t)2 * 16384 * 1536 * 2);
    u16* aoh = (u16*)alloc((size_t)2 * 4096 * 832 * 2);
    float* aff = (float*)alloc((size_t)2 * 64 * 256 * 64 * 4);
    float* den = (float*)alloc((size_t)2 * 64 * 256 * 4);
    u64* winners = (u64*)alloc((size_t)2 * 64 * 256 * 8);
    // aliases (lifetimes disjoint by stream order):
    u16* paff = lnX;               // paff == lnX region (lnX dead after kv proj)
    float* zbuf = (float*)kvb;     // zbuf (25.2MB) aliases kvb (dead after attn);
                                   // paff stays valid for prep2 in gemm_post
    if (ws_size < off) return;     // ws too small -> leave poison (diagnosable)

    // 1. weight prep; dT rows 64..127 zeroed (padding for N=128 lora GEMM)
    hipMemsetAsync(dT, 0, (size_t)128 * 768 * 2, stream);
    TPack big = {wq, wk, wv, wo, wtq, wtkv, wtkv + (size_t)768 * 768, wtoU};
    transpose_big<<<dim3(2304, 4), 256, 0, stream>>>(big);
    TPack small = {lora_down, lora_up, mlp_down, mlp_up, dT, wtoU + 768, mdT, muT};
    transpose_small<<<dim3(192, 4), 256, 0, stream>>>(small);
    hipMemsetAsync(den, 0, (size_t)2 * 64 * 256 * 4, stream);
    hipMemsetAsync(winners, 0, (size_t)2 * 64 * 256 * 8, stream);
    // 2. LN1 (wave-per-row, f4)
    ln1_kernel<<<10240, 256, 0, stream>>>(x0, x1, ln1w, ln1b, lnZ, lnX);
    // 3. q + kv projections (pure 2-way merge)
    ProjArgs pa = {lnZ, lnX, wtq, wtkv, qb, kvb};
    gemm_proj<<<3456, 256, 0, stream>>>(pa);
    // 4. lora-down (64, fills ramp) + attention (1536) in one dispatch
    AttnArgs aa = {qb, kvb, aoh, paff, lnZ, dT, aoh + 768};
    attn_mfma<<<1600, 256, 0, stream>>>(aa);
    // 5. merged (wo|up)+resid GEMM -> zbuf  AND  fusion_prep2 (one dispatch)
    PostArgs po = {aoh, wtoU, zbuf, x0, x1, paff, aff, den, winners};
    gemm_post<<<896, 256, 0, stream>>>(po);
    // 6. fused fusion-apply + LN2 + mlp lora -> single write of out (v6: 512 thr)
    fusion_ln2_mlp<<<2560, 512, 0, stream>>>(
        x0, x1, zbuf, aff, den, winners, out, ln2w, ln2b, mdT, muT);
}

// Round 20
// 332.467 us; speedup vs baseline: 1.0382x; 1.0382x over previous
//
#include <hip/hip_runtime.h>

// TMMixer: B=64, T=64, S=256, DIM=768, H=12, HD=64, RANK=64
//  1. prep_all: LN1 (10240 blocks, first) + weight transposes (9984) in ONE dispatch
//  2. gemm_proj: q + kv projections (pure, 2-way)
//  3. attn_mfma dispatch = lora-z-down (64 blocks, fills ramp) + attention (1536)
//  4. gemm_post: (wo|up) K=832 GEMM + resid -> zbuf  AND  fusion_prep2 in ONE dispatch
//  5. fusion_ln2_mlp v5 (256 thr, launch_bounds(256,2), single-winner fast path)

typedef __bf16 bf8_t __attribute__((ext_vector_type(8)));
typedef float f4_t __attribute__((ext_vector_type(4)));
typedef unsigned short u16;
typedef unsigned int u32;
typedef unsigned long long u64;
typedef unsigned short us4_t __attribute__((ext_vector_type(4)));
typedef unsigned short us8_t __attribute__((ext_vector_type(8)));

__device__ __forceinline__ float bf2f(u16 h) {
    return __uint_as_float(((unsigned int)h) << 16);
}
__device__ __forceinline__ u16 f2bf(float f) {
    unsigned int u = __float_as_uint(f);
    u += 0x7fffu + ((u >> 16) & 1u);
    return (u16)(u >> 16);
}
__device__ __forceinline__ float gelu_tanh(float x) {
    float t = tanhf(0.7978845608028654f * (x + 0.044715f * x * x * x));
    return 0.5f * x * (1.0f + t);
}
__device__ __forceinline__ void load_lds16(const void* g, void* l) {
    __builtin_amdgcn_global_load_lds(
        (const __attribute__((address_space(1))) unsigned int*)g,
        (__attribute__((address_space(3))) unsigned int*)l, 16, 0, 0);
}

// ---------------- prep_all: LN1 (0..10239) | big-T (10240..19455) | small-T
struct PrepArgs {
    const float* x0; const float* x1;
    const float* ln1w; const float* ln1b;
    u16* lnZ; u16* lnX;
    const float* wq; const float* wk; const float* wv; const float* wo;
    const float* lora_down; const float* lora_up;
    const float* mlp_down; const float* mlp_up;
    u16* wtq; u16* wtkv; u16* wtoU; u16* dT; u16* mdT; u16* muT;
};
__global__ __launch_bounds__(256) void prep_all(PrepArgs a) {
    int bid = blockIdx.x;
    int tid = threadIdx.x;
    if (bid < 10240) {
        // LN1: wave-per-row, f4 loads
        int rid = bid * 4 + (tid >> 6);
        int lane = tid & 63;
        int s = rid / 20480;
        int r2 = rid - s * 20480;
        const float* srcBase = (s == 0) ? a.x0 : a.x1;
        const float* src; u16* dst;
        if (r2 < 4096) {
            int bb = r2 >> 6, t = r2 & 63;
            src = srcBase + ((size_t)(bb * 320 + t)) * 768;
            dst = a.lnZ + ((size_t)(s * 4096 + r2)) * 768;
        } else {
            int rx = r2 - 4096;
            int bb = rx >> 8, sx = rx & 255;
            src = srcBase + ((size_t)(bb * 320 + 64 + sx)) * 768;
            dst = a.lnX + ((size_t)(s * 16384 + rx)) * 768;
        }
        f4_t v[3];
        float s1 = 0.f, s2 = 0.f;
        #pragma unroll
        for (int jj = 0; jj < 3; jj++) {
            v[jj] = *reinterpret_cast<const f4_t*>(src + (lane + 64 * jj) * 4);
            #pragma unroll
            for (int e = 0; e < 4; e++) { s1 += v[jj][e]; s2 += v[jj][e] * v[jj][e]; }
        }
        #pragma unroll
        for (int o = 1; o < 64; o <<= 1) { s1 += __shfl_xor(s1, o); s2 += __shfl_xor(s2, o); }
        float mean = s1 * (1.0f / 768.0f);
        float var = s2 * (1.0f / 768.0f) - mean * mean;
        float rstd = rsqrtf(var + 1e-5f);
        #pragma unroll
        for (int jj = 0; jj < 3; jj++) {
            int c0 = (lane + 64 * jj) * 4;
            f4_t wv = *reinterpret_cast<const f4_t*>(a.ln1w + c0);
            f4_t bv = *reinterpret_cast<const f4_t*>(a.ln1b + c0);
            us4_t o4;
            #pragma unroll
            for (int e = 0; e < 4; e++)
                o4[e] = f2bf((v[jj][e] - mean) * rstd * wv[e] + bv[e]);
            *reinterpret_cast<us4_t*>(dst + c0) = o4;
        }
    } else if (bid < 19456) {
        // big transposes: dst[C][R] = bf16(src[R][C]), 768x768 each
        int tb = bid - 10240;
        int which = tb / 2304;
        int idx = (tb % 2304) * 256 + tid;
        const float* src = which == 0 ? a.wq : which == 1 ? a.wk : which == 2 ? a.wv : a.wo;
        int c = idx / 768, r = idx - c * 768;
        u16 v = f2bf(src[(size_t)r * 768 + c]);
        if (which == 0) a.wtq[idx] = v;
        else if (which == 1) a.wtkv[idx] = v;
        else if (which == 2) a.wtkv[(size_t)768 * 768 + idx] = v;
        else a.wtoU[(size_t)c * 832 + r] = v;
    } else {
        // small transposes (49152 elems each)
        int ts = bid - 19456;
        int which = ts / 192;
        int idx = (ts % 192) * 256 + tid;
        const float* src = which == 0 ? a.lora_down : which == 1 ? a.lora_up
                          : which == 2 ? a.mlp_down : a.mlp_up;
        int R = (which & 1) ? 64 : 768;
        int C = (which & 1) ? 768 : 64;
        int c = idx / R, r = idx - c * R;
        u16 v = f2bf(src[(size_t)r * C + c]);
        if (which == 0) a.dT[idx] = v;
        else if (which == 1) a.wtoU[(size_t)c * 832 + 768 + r] = v;
        else if (which == 2) a.mdT[idx] = v;
        else a.muT[idx] = v;
    }
}

// ---------------- shared MFMA GEMM core: C = A(MxKT) * Bt(NxKT)^T ---------
enum { EPI_BF16 = 0, EPI_RESID_Z = 1, EPI_GELU64 = 2 };

template <int BM, int BN, int WR, int WC, int EPI, int KT>
__device__ __forceinline__ void gemm_core(
    u16* shA, u16* shB,
    const u16* __restrict__ A, const u16* __restrict__ Bt,
    int M, int N, int ldc, int xb, int bid,
    float* __restrict__ Cf, u16* __restrict__ Cbf,
    const float* __restrict__ resid0, const float* __restrict__ resid1) {
    constexpr int THREADS = WR * WC * 64;
    constexpr int NW = THREADS / 64;
    constexpr int BK = 64;

    const int tid = threadIdx.x;
    const int lane = tid & 63;
    const int w = tid >> 6;
    const int wr = w / WC, wc = w % WC;
    const int r = lane & 15, g = lane >> 4;
    const int gx = N / BN;
    const int panels = (M / BM) >> 3;   // requires (M/BM)%8==0
    int xcd = bid & 7, local = bid >> 3;
    const int bcol = (local % gx) * BN;
    const int brow = (xcd * panels + local / gx) * BM;

    const int srow = lane >> 3;            // row within 8-row chunk
    const int scol = (lane & 7) ^ srow;    // pre-swizzled 16B-chunk index
    const int rsw = r & 7;                 // read-side swizzle key
    const int csw0 = (g ^ rsw) * 8;
    const int csw1 = ((g + 4) ^ rsw) * 8;
    int aoff[4], boff[4];
    #pragma unroll
    for (int m = 0; m < 4; m++) aoff[m] = (wr * 64 + m * 16 + r) * 64;
    #pragma unroll
    for (int n = 0; n < 4; n++) boff[n] = (wc * 64 + n * 16 + r) * 64;

    f4_t acc[4][4];
    f4_t zero = {0.f, 0.f, 0.f, 0.f};
    #pragma unroll
    for (int m = 0; m < 4; m++)
        #pragma unroll
        for (int n = 0; n < 4; n++) acc[m][n] = zero;

    for (int k0 = 0; k0 < KT; k0 += BK) {
        #pragma unroll
        for (int c = 0; c < BM / 8 / NW; c++) {
            int chunk = w + c * NW;
            int row = chunk * 8 + srow;
            load_lds16(A + (size_t)(brow + row) * KT + k0 + scol * 8, shA + chunk * 512);
        }
        #pragma unroll
        for (int c = 0; c < BN / 8 / NW; c++) {
            int chunk = w + c * NW;
            int row = chunk * 8 + srow;
            load_lds16(Bt + (size_t)(bcol + row) * KT + k0 + scol * 8, shB + chunk * 512);
        }
        __syncthreads();
        {
            bf8_t af[4], bfr[4];
            #pragma unroll
            for (int m = 0; m < 4; m++)
                af[m] = *reinterpret_cast<const bf8_t*>(&shA[aoff[m] + csw0]);
            #pragma unroll
            for (int n = 0; n < 4; n++)
                bfr[n] = *reinterpret_cast<const bf8_t*>(&shB[boff[n] + csw0]);
            #pragma unroll
            for (int m = 0; m < 4; m++)
                #pragma unroll
                for (int n = 0; n < 4; n++)
                    acc[m][n] = __builtin_amdgcn_mfma_f32_16x16x32_bf16(af[m], bfr[n], acc[m][n], 0, 0, 0);
            #pragma unroll
            for (int m = 0; m < 4; m++)
                af[m] = *reinterpret_cast<const bf8_t*>(&shA[aoff[m] + csw1]);
            #pragma unroll
            for (int n = 0; n < 4; n++)
                bfr[n] = *reinterpret_cast<const bf8_t*>(&shB[boff[n] + csw1]);
            #pragma unroll
            for (int m = 0; m < 4; m++)
                #pragma unroll
                for (int n = 0; n < 4; n++)
                    acc[m][n] = __builtin_amdgcn_mfma_f32_16x16x32_bf16(af[m], bfr[n], acc[m][n], 0, 0, 0);
        }
        __syncthreads();
    }

    #pragma unroll
    for (int m = 0; m < 4; m++) {
        #pragma unroll
        for (int n = 0; n < 4; n++) {
            int col = bcol + wc * 64 + n * 16 + r;
            #pragma unroll
            for (int i = 0; i < 4; i++) {
                int row = brow + wr * 64 + m * 16 + g * 4 + i;
                int orow = row ^ xb;
                float val = acc[m][n][i];
                if constexpr (EPI == EPI_BF16) {
                    Cbf[(size_t)orow * ldc + col] = f2bf(val);
                } else if constexpr (EPI == EPI_RESID_Z) {
                    int s = orow >> 12, bb = (orow >> 6) & 63, t = orow & 63;
                    const float* rp = (s != 0) ? resid1 : resid0;
                    float rs = rp[((size_t)bb * 320 + t) * 768 + col];
                    Cf[(size_t)orow * 768 + col] = val + rs;   // compact zbuf
                } else if constexpr (EPI == EPI_GELU64) {
                    if (col < 64)   // N padded to 128; cols 64..127 are junk
                        Cbf[(size_t)orow * ldc + col] = f2bf(gelu_tanh(val));
                }
            }
        }
    }
}

// ---------------- gemm_proj: q (384) | kv (3072) -- pure 2-way ------------
struct ProjArgs {
    const u16* lnZ; const u16* lnX; const u16* wtq; const u16* wtkv;
    u16* qb; u16* kvb;
};
__global__ __launch_bounds__(256, 1) void gemm_proj(ProjArgs a) {
    __shared__ alignas(16) u16 SH[16384];   // 32 KB
    int bid = blockIdx.x;
    if (bid < 384) {
        gemm_core<128, 128, 2, 2, EPI_BF16, 768>(
            SH, SH + 8192, a.lnZ, a.wtq, 8192, 768, 768, 0, bid,
            nullptr, a.qb, nullptr, nullptr);
    } else {
        gemm_core<128, 128, 2, 2, EPI_BF16, 768>(
            SH, SH + 8192, a.lnX, a.wtkv, 32768, 1536, 1536, 16384, bid - 384,
            nullptr, a.kvb, nullptr, nullptr);
    }
}

// ---------------- attn dispatch: lora-down (64) + attention (1536) --------
struct AttnArgs {
    const u16* q; const u16* kv; u16* aoh; u16* paff;
    const u16* lnZ; const u16* dT; u16* aohL;   // aohL = aoh + 768
};
__global__ __launch_bounds__(256, 2) void attn_mfma(AttnArgs a) {
    __shared__ alignas(16) u16 Ks[256][72];   // 36,864 B (P tiles alias after sync)
    __shared__ alignas(16) u16 Vt[64][264];   // 33,792 B
    int bid0 = blockIdx.x;
    if (bid0 < 64) {
        // lora-z down: gelu(lnZ @ dT^T), row^4096; dT padded to N=128
        u16* SH = &Ks[0][0];   // 32 KB carve of attn's 70.7 KB LDS
        gemm_core<128, 128, 2, 2, EPI_GELU64, 768>(
            SH, SH + 8192, a.lnZ, a.dT, 8192, 128, 832, 4096, bid0,
            nullptr, a.aohL, nullptr, nullptr);
        return;
    }
    int bid = bid0 - 64;
    const u16* q = a.q;
    const u16* kv = a.kv;
    u16* aoh = a.aoh;
    u16* paff = a.paff;
    int s = bid / 768;
    int rem = bid - s * 768;
    int b = rem / 12, h = rem - (rem / 12) * 12;
    int tid = threadIdx.x, lane = tid & 63, w = tid >> 6;
    int r = lane & 15, g = lane >> 4;

    size_t kvbase = ((size_t)(s * 16384 + b * 256)) * 1536 + h * 64;

    const u16* qrow = q + ((size_t)(s * 4096 + b * 64 + w * 16 + r)) * 768 + h * 64 + g * 8;
    bf8_t qf0 = *reinterpret_cast<const bf8_t*>(qrow);
    bf8_t qf1 = *reinterpret_cast<const bf8_t*>(qrow + 32);

    #pragma unroll
    for (int i = 0; i < 8; i++) {
        int c = tid + 256 * i;
        int row = c >> 3, kc = (c & 7) * 8;
        *reinterpret_cast<bf8_t*>(&Ks[row][kc]) =
            *reinterpret_cast<const bf8_t*>(kv + kvbase + (size_t)row * 1536 + kc);
    }
    u32* vt32 = reinterpret_cast<u32*>(&Vt[0][0]);  // row stride 132 u32
    #pragma unroll
    for (int i = 0; i < 4; i++) {
        int c = tid + 256 * i;
        int kp = c >> 3, d0 = (c & 7) * 8;
        const u16* vr = kv + kvbase + 768 + (size_t)(2 * kp) * 1536 + d0;
        us8_t va = *reinterpret_cast<const us8_t*>(vr);
        us8_t vb = *reinterpret_cast<const us8_t*>(vr + 1536);
        #pragma unroll
        for (int j = 0; j < 8; j++)
            vt32[(d0 + j) * 132 + kp] = (u32)va[j] | ((u32)vb[j] << 16);
    }
    __syncthreads();

    f4_t acc[16];
    f4_t zero = {0.f, 0.f, 0.f, 0.f};
    #pragma unroll
    for (int n = 0; n < 16; n++) acc[n] = zero;
    #pragma unroll
    for (int n = 0; n < 16; n++) {
        bf8_t b0 = *reinterpret_cast<const bf8_t*>(&Ks[n * 16 + r][g * 8]);
        acc[n] = __builtin_amdgcn_mfma_f32_16x16x32_bf16(qf0, b0, acc[n], 0, 0, 0);
        bf8_t b1 = *reinterpret_cast<const bf8_t*>(&Ks[n * 16 + r][32 + g * 8]);
        acc[n] = __builtin_amdgcn_mfma_f32_16x16x32_bf16(qf1, b1, acc[n], 0, 0, 0);
    }

    float mx[4] = {-1e30f, -1e30f, -1e30f, -1e30f};
    #pragma unroll
    for (int n = 0; n < 16; n++)
        #pragma unroll
        for (int i = 0; i < 4; i++) {
            acc[n][i] *= 0.125f;
            mx[i] = fmaxf(mx[i], acc[n][i]);
        }
    #pragma unroll
    for (int i = 0; i < 4; i++) {
        mx[i] = fmaxf(mx[i], __shfl_xor(mx[i], 1));
        mx[i] = fmaxf(mx[i], __shfl_xor(mx[i], 2));
        mx[i] = fmaxf(mx[i], __shfl_xor(mx[i], 4));
        mx[i] = fmaxf(mx[i], __shfl_xor(mx[i], 8));
    }
    float sm[4] = {0.f, 0.f, 0.f, 0.f};
    #pragma unroll
    for (int n = 0; n < 16; n++)
        #pragma unroll
        for (int i = 0; i < 4; i++) {
            float e = __expf(acc[n][i] - mx[i]);
            acc[n][i] = e;
            sm[i] += e;
        }
    #pragma unroll
    for (int i = 0; i < 4; i++) {
        sm[i] += __shfl_xor(sm[i], 1);
        sm[i] += __shfl_xor(sm[i], 2);
        sm[i] += __shfl_xor(sm[i], 4);
        sm[i] += __shfl_xor(sm[i], 8);
    }
    float inv[4];
    #pragma unroll
    for (int i = 0; i < 4; i++) inv[i] = 1.0f / sm[i];

    __syncthreads();  // all waves done reading Ks; safe to overwrite with P

    u16* Pw = &Ks[w * 64][0];
    u16* pout = paff + ((size_t)bid * 64 + w * 16) * 256;
    #pragma unroll
    for (int n = 0; n < 16; n++) {
        int kcol = n * 16 + r;
        #pragma unroll
        for (int i = 0; i < 4; i++) {
            u16 pb = f2bf(acc[n][i] * inv[i]);
            Pw[(g * 4 + i) * 264 + kcol] = pb;
            pout[(g * 4 + i) * 256 + kcol] = pb;
        }
    }

    f4_t acc2[4];
    #pragma unroll
    for (int n = 0; n < 4; n++) acc2[n] = zero;
    #pragma unroll
    for (int k2 = 0; k2 < 8; k2++) {
        bf8_t pa = *reinterpret_cast<const bf8_t*>(&Pw[r * 264 + k2 * 32 + g * 8]);
        #pragma unroll
        for (int n2 = 0; n2 < 4; n2++) {
            bf8_t vbf = *reinterpret_cast<const bf8_t*>(&Vt[n2 * 16 + r][k2 * 32 + g * 8]);
            acc2[n2] = __builtin_amdgcn_mfma_f32_16x16x32_bf16(pa, vbf, acc2[n2], 0, 0, 0);
        }
    }
    u16* op = aoh + ((size_t)(s * 4096 + b * 64 + w * 16 + g * 4)) * 832 + h * 64;
    #pragma unroll
    for (int n2 = 0; n2 < 4; n2++)
        #pragma unroll
        for (int i = 0; i < 4; i++)
            op[(size_t)i * 832 + n2 * 16 + r] = f2bf(acc2[n2][i]);
}

// ---------------- prep2 body (device): h-sum -> colmax -> nu/den/winners --
__device__ __forceinline__ void prep2_body(
    int idx, const u16* __restrict__ paff, float* __restrict__ aff,
    float* __restrict__ den, u64* __restrict__ winners, float* red) {
    int sb = idx & 127, qc = idx >> 7;
    int t = threadIdx.x, lane = t & 63, w = t >> 6;
    int q0 = qc * 16;
    float a[16];
    #pragma unroll
    for (int j = 0; j < 16; j++) a[j] = 0.f;
    size_t base = ((size_t)sb * 12 * 64 + q0) * 256 + t;
    for (int h = 0; h < 12; h++) {
        size_t hb = base + (size_t)h * 64 * 256;
        #pragma unroll
        for (int j = 0; j < 16; j++) a[j] += bf2f(paff[hb + j * 256]);
    }
    float m[16];
    #pragma unroll
    for (int j = 0; j < 16; j++) {
        float v = a[j];
        #pragma unroll
        for (int o = 1; o < 64; o <<= 1) v = fmaxf(v, __shfl_xor(v, o));
        m[j] = v;
    }
    if (lane == 0) {
        #pragma unroll
        for (int j = 0; j < 16; j++) red[j * 4 + w] = m[j];
    }
    __syncthreads();
    float dsum = 0.f;
    u64 wmask = 0;
    float nu[16];
    #pragma unroll
    for (int j = 0; j < 16; j++) {
        float cm = fmaxf(fmaxf(red[j * 4 + 0], red[j * 4 + 1]),
                         fmaxf(red[j * 4 + 2], red[j * 4 + 3]));
        nu[j] = (a[j] == cm) ? __expf(a[j] - 12.0f) : 0.f;
        if (nu[j] != 0.f) wmask |= (u64)1 << (q0 + j);
        dsum += nu[j];
    }
    if (dsum != 0.f) atomicAdd(&den[sb * 256 + t], dsum);
    if (wmask) atomicOr(&winners[(size_t)sb * 256 + t], wmask);
    float* ap = aff + ((size_t)sb * 256 + t) * 64 + q0;
    #pragma unroll
    for (int j = 0; j < 16; j++) ap[j] = nu[j];
}

// ---------------- gemm_post: wo|up GEMM (384) | fusion_prep2 (512) --------
struct PostArgs {
    const u16* aoh; const u16* wtoU; float* zbuf;
    const float* x0; const float* x1;
    const u16* paff; float* aff; float* den; u64* winners;
};
__global__ __launch_bounds__(256, 1) void gemm_post(PostArgs a) {
    __shared__ alignas(16) u16 SH[16384];   // 32 KB
    int bid = blockIdx.x;
    if (bid < 384) {
        gemm_core<128, 128, 2, 2, EPI_RESID_Z, 832>(
            SH, SH + 8192, a.aoh, a.wtoU, 8192, 768, 768, 0, bid,
            a.zbuf, nullptr, a.x0, a.x1);
    } else {
        prep2_body(bid - 384, a.paff, a.aff, a.den, a.winners, (float*)SH);
    }
}

// ---------------- fusion_ln2_mlp v5: 256 thr, single-winner fast path -----
__global__ __launch_bounds__(256, 2) void fusion_ln2_mlp(
    const float* __restrict__ x0, const float* __restrict__ x1,
    const float* __restrict__ zbuf, const float* __restrict__ aff,
    const float* __restrict__ den, const u64* __restrict__ winners,
    float* __restrict__ out, const float* __restrict__ w2,
    const float* __restrict__ b2, const u16* __restrict__ mdT,
    const u16* __restrict__ muT) {
    __shared__ alignas(16) u16 A[16][776];   // 24,832 B; reused for up-contribution
    __shared__ alignas(16) u16 Hs[16][72];   //  2,304 B
    int tid = threadIdx.x, lane = tid & 63, w = tid >> 6;
    int r = lane & 15, g = lane >> 4;
    int rbase = blockIdx.x * 16;

    // phase 0a: per-row metadata
    const float* srcp[4];
    float scale[4];
    u64 masks[4];
    int sbx[4], sxx[4], sss[4];
    #pragma unroll
    for (int rr = 0; rr < 4; rr++) {
        int rid = rbase + w * 4 + rr;
        int s = rid / 20480;
        int r2 = rid - s * 20480;
        int b = r2 / 320, n = r2 - (r2 / 320) * 320;
        sss[rr] = s; sbx[rr] = b;
        if (n < 64) {
            srcp[rr] = zbuf + ((size_t)(s * 4096 + b * 64 + n)) * 768;
            scale[rr] = 1.0f;
            masks[rr] = 0;
            sxx[rr] = 0;
        } else {
            int sx = n - 64;
            int sb = s * 64 + b;
            srcp[rr] = ((s == 0) ? x0 : x1) + ((size_t)(b * 320 + n)) * 768;
            scale[rr] = 1.0f / (1.0f + den[sb * 256 + sx]);
            masks[rr] = winners[(size_t)sb * 256 + sx];
            sxx[rr] = sx;
        }
    }
    // phase 0b: all base loads issued back-to-back (one HBM volley)
    f4_t p[4][3];
    #pragma unroll
    for (int rr = 0; rr < 4; rr++)
        #pragma unroll
        for (int cc = 0; cc < 3; cc++)
            p[rr][cc] = *reinterpret_cast<const f4_t*>(srcp[rr] + cc * 256 + lane * 4);
    // phase 0c: gathers (single-winner fast path; wave-uniform branch)
    u64 many = (masks[0] & (masks[0] - 1)) | (masks[1] & (masks[1] - 1)) |
               (masks[2] & (masks[2] - 1)) | (masks[3] & (masks[3] - 1));
    u64 anyw = masks[0] | masks[1] | masks[2] | masks[3];
    if (many == 0) {
        if (anyw) {
            int wt[4];
            float wnu[4];
            #pragma unroll
            for (int rr = 0; rr < 4; rr++)
                wt[rr] = masks[rr] ? (int)__builtin_ctzll(masks[rr]) : 0;
            #pragma unroll
            for (int rr = 0; rr < 4; rr++) {
                size_t sb = (size_t)(sss[rr] * 64 + sbx[rr]);
                wnu[rr] = aff[(sb * 256 + sxx[rr]) * 64 + wt[rr]];
            }
            f4_t zv[4][3];
            #pragma unroll
            for (int rr = 0; rr < 4; rr++) {
                const float* zr = zbuf + ((size_t)(sss[rr] * 4096 + sbx[rr] * 64 + wt[rr])) * 768;
                #pragma unroll
                for (int cc = 0; cc < 3; cc++)
                    zv[rr][cc] = *reinterpret_cast<const f4_t*>(zr + cc * 256 + lane * 4);
            }
            #pragma unroll
            for (int rr = 0; rr < 4; rr++) {
                float wgt = masks[rr] ? wnu[rr] * scale[rr] : 0.f;
                #pragma unroll
                for (int cc = 0; cc < 3; cc++)
                    p[rr][cc] = p[rr][cc] * scale[rr] + zv[rr][cc] * wgt;
            }
        }
    } else {
        #pragma unroll
        for (int rr = 0; rr < 4; rr++) {
            #pragma unroll
            for (int cc = 0; cc < 3; cc++) p[rr][cc] *= scale[rr];
            u64 mask = masks[rr];
            while (mask) {
                int t = (int)__builtin_ctzll(mask);
                mask &= mask - 1;
                int sb = sss[rr] * 64 + sbx[rr];
                float wgt = aff[((size_t)sb * 256 + sxx[rr]) * 64 + t] * scale[rr];
                const float* zr = zbuf + ((size_t)(sss[rr] * 4096 + sbx[rr] * 64 + t)) * 768;
                #pragma unroll
                for (int cc = 0; cc < 3; cc++)
                    p[rr][cc] += *reinterpret_cast<const f4_t*>(zr + cc * 256 + lane * 4) * wgt;
            }
        }
    }
    // phase 0d: hoisted w2/b2 + per-row LN reduce + A write
    f4_t wv[3], bv[3];
    #pragma unroll
    for (int cc = 0; cc < 3; cc++) {
        wv[cc] = *reinterpret_cast<const f4_t*>(w2 + cc * 256 + lane * 4);
        bv[cc] = *reinterpret_cast<const f4_t*>(b2 + cc * 256 + lane * 4);
    }
    #pragma unroll
    for (int rr = 0; rr < 4; rr++) {
        float a1 = 0.f, a2 = 0.f;
        #pragma unroll
        for (int cc = 0; cc < 3; cc++)
            #pragma unroll
            for (int e = 0; e < 4; e++) { a1 += p[rr][cc][e]; a2 += p[rr][cc][e] * p[rr][cc][e]; }
        #pragma unroll
        for (int o = 1; o < 64; o <<= 1) { a1 += __shfl_xor(a1, o); a2 += __shfl_xor(a2, o); }
        float mean = a1 * (1.0f / 768.0f);
        float var = a2 * (1.0f / 768.0f) - mean * mean;
        float rstd = rsqrtf(var + 1e-5f);
        int row = w * 4 + rr;
        #pragma unroll
        for (int cc = 0; cc < 3; cc++) {
            int c0 = cc * 256 + lane * 4;
            us4_t o4;
            #pragma unroll
            for (int e = 0; e < 4; e++)
                o4[e] = f2bf((p[rr][cc][e] - mean) * rstd * wv[cc][e] + bv[cc][e]);
            *reinterpret_cast<us4_t*>(&A[row][c0]) = o4;
        }
    }
    __syncthreads();

    // phase 1: down GEMM (M=16, N=64, K=768); fully unrolled, hoisted mdT ptr
    f4_t zero = {0.f, 0.f, 0.f, 0.f};
    f4_t hacc = zero;
    const u16* mrow = mdT + (size_t)(w * 16 + r) * 768 + g * 8;
    #pragma unroll
    for (int k0 = 0; k0 < 768; k0 += 32) {
        bf8_t af = *reinterpret_cast<const bf8_t*>(&A[r][k0 + g * 8]);
        bf8_t bf = *reinterpret_cast<const bf8_t*>(mrow + k0);
        hacc = __builtin_amdgcn_mfma_f32_16x16x32_bf16(af, bf, hacc, 0, 0, 0);
    }
    #pragma unroll
    for (int i = 0; i < 4; i++)
        Hs[g * 4 + i][w * 16 + r] = f2bf(gelu_tanh(hacc[i]));
    __syncthreads();   // Hs ready; all A reads done

    // phase 2: up GEMM (M=16, N=768, K=64); wave w owns cols w*192..w*192+191
    bf8_t a0 = *reinterpret_cast<const bf8_t*>(&Hs[r][g * 8]);
    bf8_t a1 = *reinterpret_cast<const bf8_t*>(&Hs[r][32 + g * 8]);
    #pragma unroll
    for (int nn = 0; nn < 12; nn++) {
        int col = w * 192 + nn * 16 + r;
        bf8_t b0 = *reinterpret_cast<const bf8_t*>(muT + (size_t)col * 64 + g * 8);
        bf8_t b1 = *reinterpret_cast<const bf8_t*>(muT + (size_t)col * 64 + 32 + g * 8);
        f4_t c = __builtin_amdgcn_mfma_f32_16x16x32_bf16(a1, b1, zero, 0, 0, 0);
        c = __builtin_amdgcn_mfma_f32_16x16x32_bf16(a0, b0, c, 0, 0, 0);
        #pragma unroll
        for (int i = 0; i < 4; i++)
            A[g * 4 + i][col] = f2bf(c[i]);
    }
    __syncthreads();

    // phase 3: coalesced add + single store of out
    #pragma unroll
    for (int rr = 0; rr < 4; rr++) {
        int row = w * 4 + rr;
        size_t orow = (size_t)(rbase + row) * 768;
        #pragma unroll
        for (int cc = 0; cc < 3; cc++) {
            int c0 = cc * 256 + lane * 4;
            us4_t c4 = *reinterpret_cast<const us4_t*>(&A[row][c0]);
            f4_t o = p[rr][cc];
            #pragma unroll
            for (int e = 0; e < 4; e++) o[e] += bf2f(c4[e]);
            *reinterpret_cast<f4_t*>(out + orow + c0) = o;
        }
    }
}

extern "C" void kernel_launch(void* const* d_in, const int* in_sizes, int n_in,
                              void* d_out, int out_size, void* d_ws, size_t ws_size,
                              hipStream_t stream) {
    (void)in_sizes; (void)n_in; (void)out_size;
    const float* x0 = (const float*)d_in[0];
    const float* x1 = (const float*)d_in[1];
    const float* ln1w = (const float*)d_in[2];
    const float* ln1b = (const float*)d_in[3];
    const float* ln2w = (const float*)d_in[4];
    const float* ln2b = (const float*)d_in[5];
    const float* wq = (const float*)d_in[6];
    const float* wk = (const float*)d_in[7];
    const float* wv = (const float*)d_in[8];
    const float* wo = (const float*)d_in[9];
    const float* lora_down = (const float*)d_in[10];
    const float* lora_up = (const float*)d_in[11];
    const float* mlp_down = (const float*)d_in[12];
    const float* mlp_up = (const float*)d_in[13];
    float* out = (float*)d_out;

    char* ws = (char*)d_ws;
    size_t off = 0;
    auto alloc = [&](size_t bytes) -> char* {
        char* p = ws + off;
        off = (off + bytes + 255) & ~(size_t)255;
        return p;
    };
    u16* wtq  = (u16*)alloc(768 * 768 * 2);
    u16* wtkv = (u16*)alloc((size_t)1536 * 768 * 2);
    u16* wtoU = (u16*)alloc((size_t)768 * 832 * 2);
    u16* dT  = (u16*)alloc((size_t)128 * 768 * 2);   // padded to 128 rows
    u16* mdT = (u16*)alloc(768 * 64 * 2);
    u16* muT = (u16*)alloc(768 * 64 * 2);
    u16* lnZ = (u16*)alloc((size_t)2 * 4096 * 768 * 2);
    u16* lnX = (u16*)alloc((size_t)2 * 16384 * 768 * 2);
    u16* qb  = (u16*)alloc((size_t)2 * 4096 * 768 * 2);
    u16* kvb = (u16*)alloc((size_t)2 * 16384 * 1536 * 2);
    u16* aoh = (u16*)alloc((size_t)2 * 4096 * 832 * 2);
    float* aff = (float*)alloc((size_t)2 * 64 * 256 * 64 * 4);
    float* den = (float*)alloc((size_t)2 * 64 * 256 * 4);
    u64* winners = (u64*)alloc((size_t)2 * 64 * 256 * 8);
    // aliases (lifetimes disjoint by stream order):
    u16* paff = lnX;               // paff == lnX region (lnX dead after kv proj)
    float* zbuf = (float*)kvb;     // zbuf (25.2MB) aliases kvb (dead after attn);
                                   // paff stays valid for prep2 in gemm_post
    if (ws_size < off) return;     // ws too small -> leave poison (diagnosable)

    // 0. memsets (dT pad rows; den/winners accumulators)
    hipMemsetAsync(dT, 0, (size_t)128 * 768 * 2, stream);
    hipMemsetAsync(den, 0, (size_t)2 * 64 * 256 * 4, stream);
    hipMemsetAsync(winners, 0, (size_t)2 * 64 * 256 * 8, stream);
    // 1. prep_all: LN1 + all weight transposes in one dispatch
    PrepArgs pr = {x0, x1, ln1w, ln1b, lnZ, lnX,
                   wq, wk, wv, wo, lora_down, lora_up, mlp_down, mlp_up,
                   wtq, wtkv, wtoU, dT, mdT, muT};
    prep_all<<<20224, 256, 0, stream>>>(pr);
    // 2. q + kv projections (pure 2-way merge)
    ProjArgs pa = {lnZ, lnX, wtq, wtkv, qb, kvb};
    gemm_proj<<<3456, 256, 0, stream>>>(pa);
    // 3. lora-down (64, fills ramp) + attention (1536) in one dispatch
    AttnArgs aa = {qb, kvb, aoh, paff, lnZ, dT, aoh + 768};
    attn_mfma<<<1600, 256, 0, stream>>>(aa);
    // 4. merged (wo|up)+resid GEMM -> zbuf  AND  fusion_prep2 (one dispatch)
    PostArgs po = {aoh, wtoU, zbuf, x0, x1, paff, aff, den, winners};
    gemm_post<<<896, 256, 0, stream>>>(po);
    // 5. fused fusion-apply + LN2 + mlp lora -> single write of out (v5)
    fusion_ln2_mlp<<<2560, 256, 0, stream>>>(
        x0, x1, zbuf, aff, den, winners, out, ln2w, ln2b, mdT, muT);
}